// Round 1
// baseline (433.697 us; speedup 1.0000x reference)
//
#include <hip/hip_runtime.h>
#include <math.h>

// ---------------- workspace layout (floats) ----------------
// wt_stft [256][258]            @ 0        (66048)
// w1t     [129][3][128]         @ 66048    (49536)
// w2t     [128][3][64]          @ 115584   (24576)
// w3t     [64][3][64]           @ 140160   (12288)
// w4t     [64][128]             @ 152448   (8192)
// wiht    [128][512]            @ 160640   (65536)
// whht    [128][512]            @ 226176   (65536)
// feat    [B][128]              @ 291712   (B*128)
#define OFF_W1T   66048
#define OFF_W2T   115584
#define OFF_W3T   140160
#define OFF_W4T   152448
#define OFF_WIHT  160640
#define OFF_WHHT  226176
#define OFF_FEAT  291712
#define PREP_N    291712

__device__ __forceinline__ float sigf(float v) { return 1.f / (1.f + expf(-v)); }

// ---------------- kernel 0: weight transposes ----------------
__global__ __launch_bounds__(256) void prep_kernel(
    const float* __restrict__ stft_w, const float* __restrict__ w1,
    const float* __restrict__ w2, const float* __restrict__ w3,
    const float* __restrict__ w4, const float* __restrict__ wih,
    const float* __restrict__ whh, float* __restrict__ ws)
{
    int i = blockIdx.x * 256 + threadIdx.x;
    if (i < 66048) {                 // wt_stft[k][o] = stft_w[o][0][k]
        int k = i / 258, o = i - k * 258;
        ws[i] = stft_w[o * 256 + k];
        return;
    }
    i -= 66048;
    if (i < 49536) {                 // w1t[f][k][c] = w1[c][f][k]  (128,129,3)
        int f = i / 384, r = i - f * 384, k = r >> 7, c = r & 127;
        ws[OFF_W1T + i] = w1[c * 387 + f * 3 + k];
        return;
    }
    i -= 49536;
    if (i < 24576) {                 // w2t[f][k][c] = w2[c][f][k]  (64,128,3)
        int f = i / 192, r = i - f * 192, k = r >> 6, c = r & 63;
        ws[OFF_W2T + i] = w2[c * 384 + f * 3 + k];
        return;
    }
    i -= 24576;
    if (i < 12288) {                 // w3t[f][k][c] = w3[c][f][k]  (64,64,3)
        int f = i / 192, r = i - f * 192, k = r >> 6, c = r & 63;
        ws[OFF_W3T + i] = w3[c * 192 + f * 3 + k];
        return;
    }
    i -= 12288;
    if (i < 8192) {                  // w4t[f][c] = w4[c][f][1]     (128,64,3)
        int f = i >> 7, c = i & 127;
        ws[OFF_W4T + i] = w4[c * 192 + f * 3 + 1];
        return;
    }
    i -= 8192;
    if (i < 65536) {                 // wiht[c][j] = w_ih[j][c]     (512,128)
        int c = i >> 9, j = i & 511;
        ws[OFF_WIHT + i] = wih[j * 128 + c];
        return;
    }
    i -= 65536;
    if (i < 65536) {                 // whht[c][j] = w_hh[j][c]
        int c = i >> 9, j = i & 511;
        ws[OFF_WHHT + i] = whh[j * 128 + c];
        return;
    }
}

// ---------------- kernel 1: fused STFT + mag + conv1..4 ----------------
// block = 256 threads, 8 batch elements per block.
__global__ __launch_bounds__(256) void feat_kernel(
    const float* __restrict__ x, const float* __restrict__ ws,
    const float* __restrict__ b1, const float* __restrict__ b2,
    const float* __restrict__ b3, const float* __restrict__ b4,
    float* __restrict__ featg)
{
    __shared__ float A[4096];   // xs[8][512]; later h0[(b*3+t)][132]
    __shared__ float Bu[6208];  // s[(b*3+t)][258]; later h1[(b*3+t)][128] | h2@3072 | h3@4096

    const float* wt_stft = ws;
    const float* w1t = ws + OFF_W1T;
    const float* w2t = ws + OFF_W2T;
    const float* w3t = ws + OFF_W3T;
    const float* w4t = ws + OFF_W4T;

    const int tid = threadIdx.x;
    const long base = (long)blockIdx.x * (8 * 512);

    // ---- A: stage x (contiguous 16 KB) ----
    {
        const float4* xg = (const float4*)(x + base);
        float4* xs4 = (float4*)A;
#pragma unroll
        for (int i = 0; i < 4; ++i) xs4[tid + i * 256] = xg[tid + i * 256];
    }
    __syncthreads();

    // ---- B: STFT, lane owns channel o = tid (0..255); tail for o=256,257 ----
    {
        float acc[8][3];
#pragma unroll
        for (int b = 0; b < 8; ++b) { acc[b][0] = acc[b][1] = acc[b][2] = 0.f; }
        const int o = tid;
        for (int k = 0; k < 256; k += 4) {
            float w0 = wt_stft[(k + 0) * 258 + o];
            float w1v = wt_stft[(k + 1) * 258 + o];
            float w2v = wt_stft[(k + 2) * 258 + o];
            float w3v = wt_stft[(k + 3) * 258 + o];
#pragma unroll
            for (int b = 0; b < 8; ++b) {
                float4 x0 = *(const float4*)&A[b * 512 + k];
                float4 x1 = *(const float4*)&A[b * 512 + 128 + k];
                float4 x2 = *(const float4*)&A[b * 512 + 256 + k];
                acc[b][0] += w0 * x0.x + w1v * x0.y + w2v * x0.z + w3v * x0.w;
                acc[b][1] += w0 * x1.x + w1v * x1.y + w2v * x1.z + w3v * x1.w;
                acc[b][2] += w0 * x2.x + w1v * x2.y + w2v * x2.z + w3v * x2.w;
            }
        }
#pragma unroll
        for (int b = 0; b < 8; ++b)
#pragma unroll
            for (int t = 0; t < 3; ++t)
                Bu[(b * 3 + t) * 258 + o] = acc[b][t];
        // channels 256,257 (imag f=127,128): 48 dots handled by threads 0..47
        if (tid < 48) {
            int b = tid / 6, r = tid - b * 6;
            int t = r >> 1, o2 = 256 + (r & 1);
            float a = 0.f;
            for (int k = 0; k < 256; ++k)
                a += wt_stft[k * 258 + o2] * A[b * 512 + t * 128 + k];
            Bu[(b * 3 + t) * 258 + o2] = a;
        }
    }
    __syncthreads();

    // ---- C: magnitude -> h0 in A, layout (b*3+t)*132 + f ----
    for (int idx = tid; idx < 8 * 3 * 129; idx += 256) {
        int bt = idx / 129, f = idx - bt * 129;
        float re = Bu[bt * 258 + f];
        float im = Bu[bt * 258 + 129 + f];
        A[bt * 132 + f] = sqrtf(re * re + im * im);
    }
    __syncthreads();

    // ---- D: conv1 (129->128, k=3, pad1) -> h1 in Bu[(b*3+t)*128+c] ----
    {
        int c = tid & 127, g = tid >> 7;  // g: 0..1 -> b = 4g..4g+3
        float acc[4][3];
#pragma unroll
        for (int bb = 0; bb < 4; ++bb) acc[bb][0] = acc[bb][1] = acc[bb][2] = 0.f;
        for (int f = 0; f < 129; ++f) {
            float wk0 = w1t[(f * 3 + 0) * 128 + c];
            float wk1 = w1t[(f * 3 + 1) * 128 + c];
            float wk2 = w1t[(f * 3 + 2) * 128 + c];
#pragma unroll
            for (int bb = 0; bb < 4; ++bb) {
                int b = g * 4 + bb;
                float h0_0 = A[(b * 3 + 0) * 132 + f];
                float h0_1 = A[(b * 3 + 1) * 132 + f];
                float h0_2 = A[(b * 3 + 2) * 132 + f];
                acc[bb][1] += h0_0 * wk0;   // tk=0: k0->t1
                acc[bb][0] += h0_0 * wk1;   //       k1->t0
                acc[bb][2] += h0_1 * wk0;   // tk=1: k0->t2
                acc[bb][1] += h0_1 * wk1;   //       k1->t1
                acc[bb][0] += h0_1 * wk2;   //       k2->t0
                acc[bb][2] += h0_2 * wk1;   // tk=2: k1->t2
                acc[bb][1] += h0_2 * wk2;   //       k2->t1
            }
        }
        float bias = b1[c];
#pragma unroll
        for (int bb = 0; bb < 4; ++bb)
#pragma unroll
            for (int t = 0; t < 3; ++t)
                Bu[((g * 4 + bb) * 3 + t) * 128 + c] = fmaxf(acc[bb][t] + bias, 0.f);
    }
    __syncthreads();

    // ---- E: conv2 (128->64, k=3, s=2, pad1) -> h2 at Bu[3072 + (b*2+t2)*64+c] ----
    {
        int c = tid & 63, g = tid >> 6;   // g: 0..3 -> b = 2g, 2g+1
        float acc[2][2] = {{0.f, 0.f}, {0.f, 0.f}};
        for (int f = 0; f < 128; ++f) {
            float wk0 = w2t[(f * 3 + 0) * 64 + c];
            float wk1 = w2t[(f * 3 + 1) * 64 + c];
            float wk2 = w2t[(f * 3 + 2) * 64 + c];
#pragma unroll
            for (int bb = 0; bb < 2; ++bb) {
                int b = g * 2 + bb;
                float h1_0 = Bu[(b * 3 + 0) * 128 + f];
                float h1_1 = Bu[(b * 3 + 1) * 128 + f];
                float h1_2 = Bu[(b * 3 + 2) * 128 + f];
                acc[bb][0] += h1_0 * wk1 + h1_1 * wk2;   // t2=0: (tk0,k1),(tk1,k2)
                acc[bb][1] += h1_1 * wk0 + h1_2 * wk1;   // t2=1: (tk1,k0),(tk2,k1)
            }
        }
        float bias = b2[c];
#pragma unroll
        for (int bb = 0; bb < 2; ++bb)
#pragma unroll
            for (int t = 0; t < 2; ++t)
                Bu[3072 + ((g * 2 + bb) * 2 + t) * 64 + c] = fmaxf(acc[bb][t] + bias, 0.f);
    }
    __syncthreads();

    // ---- F: conv3 (64->64, k=3, s=2, pad1; only k=1,2 live) -> h3 at Bu[4096 + b*64+c] ----
    {
        int c = tid & 63, g = tid >> 6;   // b = 2g, 2g+1
        float acc[2] = {0.f, 0.f};
        for (int f = 0; f < 64; ++f) {
            float wk1 = w3t[(f * 3 + 1) * 64 + c];
            float wk2 = w3t[(f * 3 + 2) * 64 + c];
#pragma unroll
            for (int bb = 0; bb < 2; ++bb) {
                int b = g * 2 + bb;
                acc[bb] += Bu[3072 + (b * 2 + 0) * 64 + f] * wk1
                         + Bu[3072 + (b * 2 + 1) * 64 + f] * wk2;
            }
        }
        float bias = b3[c];
#pragma unroll
        for (int bb = 0; bb < 2; ++bb)
            Bu[4096 + (g * 2 + bb) * 64 + c] = fmaxf(acc[bb] + bias, 0.f);
    }
    __syncthreads();

    // ---- G: conv4 (64->128, only k=1 live) + relu -> feat ----
    {
        int c = tid & 127, g = tid >> 7;  // b = 4g..4g+3
        float acc[4] = {0.f, 0.f, 0.f, 0.f};
        for (int f = 0; f < 64; ++f) {
            float wv = w4t[f * 128 + c];
#pragma unroll
            for (int bb = 0; bb < 4; ++bb)
                acc[bb] += Bu[4096 + (g * 4 + bb) * 64 + f] * wv;
        }
        float bias = b4[c];
#pragma unroll
        for (int bb = 0; bb < 4; ++bb) {
            long batch = (long)blockIdx.x * 8 + g * 4 + bb;
            featg[batch * 128 + c] = fmaxf(acc[bb] + bias, 0.f);
        }
    }
}

// ---------------- kernel 2: LSTM cell + head ----------------
// block = 512 threads, 8 batch elements per block.
__global__ __launch_bounds__(512) void lstm_kernel(
    const float* __restrict__ featg, const float* __restrict__ state,
    const float* __restrict__ wiht, const float* __restrict__ whht,
    const float* __restrict__ b_ih, const float* __restrict__ b_hh,
    const float* __restrict__ fw, const float* __restrict__ fbp,
    float* __restrict__ out, int B)
{
    __shared__ float fs[8 * 128];
    __shared__ float hs[8 * 128];
    __shared__ float gl[8 * 512];
    __shared__ float red[8 * 128];

    const int tid = threadIdx.x;
    const long blk = blockIdx.x;
    const float* h_prev = state;
    const float* c_prev = state + (long)B * 128;

    for (int idx = tid; idx < 1024; idx += 512) {
        fs[idx] = featg[blk * 1024 + idx];
        hs[idx] = h_prev[blk * 1024 + idx];
    }
    __syncthreads();

    // gates: lane owns gate-row j = tid (0..511)
    {
        const int j = tid;
        float acc[8];
        float binit = b_ih[j] + b_hh[j];
#pragma unroll
        for (int b = 0; b < 8; ++b) acc[b] = binit;
        for (int c = 0; c < 128; c += 4) {
            float w0 = wiht[(c + 0) * 512 + j];
            float w1 = wiht[(c + 1) * 512 + j];
            float w2 = wiht[(c + 2) * 512 + j];
            float w3 = wiht[(c + 3) * 512 + j];
#pragma unroll
            for (int b = 0; b < 8; ++b) {
                float4 f4 = *(const float4*)&fs[b * 128 + c];
                acc[b] += w0 * f4.x + w1 * f4.y + w2 * f4.z + w3 * f4.w;
            }
        }
        for (int c = 0; c < 128; c += 4) {
            float w0 = whht[(c + 0) * 512 + j];
            float w1 = whht[(c + 1) * 512 + j];
            float w2 = whht[(c + 2) * 512 + j];
            float w3 = whht[(c + 3) * 512 + j];
#pragma unroll
            for (int b = 0; b < 8; ++b) {
                float4 h4 = *(const float4*)&hs[b * 128 + c];
                acc[b] += w0 * h4.x + w1 * h4.y + w2 * h4.z + w3 * h4.w;
            }
        }
#pragma unroll
        for (int b = 0; b < 8; ++b) gl[b * 512 + j] = acc[b];
    }
    __syncthreads();

    // elementwise LSTM + head contributions
    for (int idx = tid; idx < 1024; idx += 512) {
        int b = idx >> 7, cc = idx & 127;
        float gi = gl[b * 512 + cc];
        float gf = gl[b * 512 + 128 + cc];
        float gg = gl[b * 512 + 256 + cc];
        float go = gl[b * 512 + 384 + cc];
        float cp = c_prev[blk * 1024 + idx];
        float cn = sigf(gf) * cp + sigf(gi) * tanhf(gg);
        float hn = sigf(go) * tanhf(cn);
        out[B + blk * 1024 + idx] = hn;                    // new_state[0]
        out[B + (long)B * 128 + blk * 1024 + idx] = cn;    // new_state[1]
        red[idx] = fmaxf(hn, 0.f) * fw[cc];
    }
    __syncthreads();

    // per-b reduction of 128 contribs; wave w handles b=w
    {
        int w = tid >> 6, lane = tid & 63;
        float v = red[w * 128 + lane] + red[w * 128 + 64 + lane];
#pragma unroll
        for (int off = 32; off; off >>= 1) v += __shfl_xor(v, off, 64);
        if (lane == 0) out[blk * 8 + w] = sigf(v + fbp[0]);
    }
}

extern "C" void kernel_launch(void* const* d_in, const int* in_sizes, int n_in,
                              void* d_out, int out_size, void* d_ws, size_t ws_size,
                              hipStream_t stream) {
    const float* x      = (const float*)d_in[0];
    const float* state  = (const float*)d_in[1];
    const float* stft_w = (const float*)d_in[2];
    const float* w1     = (const float*)d_in[3];
    const float* b1     = (const float*)d_in[4];
    const float* w2     = (const float*)d_in[5];
    const float* b2     = (const float*)d_in[6];
    const float* w3     = (const float*)d_in[7];
    const float* b3     = (const float*)d_in[8];
    const float* w4     = (const float*)d_in[9];
    const float* b4     = (const float*)d_in[10];
    const float* wih    = (const float*)d_in[11];
    const float* whh    = (const float*)d_in[12];
    const float* bih    = (const float*)d_in[13];
    const float* bhh    = (const float*)d_in[14];
    const float* fw     = (const float*)d_in[15];
    const float* fbp    = (const float*)d_in[16];

    float* ws = (float*)d_ws;
    const int B = in_sizes[0] / 512;   // 16384

    prep_kernel<<<(PREP_N + 255) / 256, 256, 0, stream>>>(stft_w, w1, w2, w3, w4, wih, whh, ws);
    feat_kernel<<<B / 8, 256, 0, stream>>>(x, ws, b1, b2, b3, b4, ws + OFF_FEAT);
    lstm_kernel<<<B / 8, 512, 0, stream>>>(ws + OFF_FEAT, state, ws + OFF_WIHT, ws + OFF_WHHT,
                                           bih, bhh, fw, fbp, (float*)d_out, B);
}

// Round 2
// 83.770 us; speedup vs baseline: 5.1772x; 5.1772x over previous
//
#include <hip/hip_runtime.h>
#include <math.h>

typedef unsigned short ushort_t;
typedef short short8 __attribute__((ext_vector_type(8)));
typedef float floatx4 __attribute__((ext_vector_type(4)));

#define MFMA16(a,b,c) __builtin_amdgcn_mfma_f32_16x16x32_bf16((a),(b),(c),0,0,0)

// ---------------- ws layout (ushort/bf16 elements) ----------------
// packed weight fragments: frag = 512 elems = 64 lanes x 8 (k-contig)
#define PK_STFT 0          // 17ct x 8kk          = 69632   B[k=0..255][n=0..271], n>=258 -> 0
#define PK_W1   69632      // 3tap x (8ct x 5kk)  = 61440   B[f=0..159][c], f>=129 -> 0
#define PK_W2   131072     // 4ct x 12kk          = 24576   B[k*128+f][c]
#define PK_W3   155648     // 4ct x 6kk           = 12288   B[k*64+f][c]
#define PK_W4   167936     // 8ct x 2kk           = 8192    B[f=0..63][c]  (tap k=1 only)
#define PK_LSTM 176128     // 32ct x 8kk          = 131072  B[k=0..255][n], k<128: w_ih, else w_hh
#define OFF_MAG 307200     // [B][3][160] bf16
#define OFF_FEAT 8171520   // [B][128] bf16

__device__ __forceinline__ ushort_t f2bf(float f){
    unsigned int u = __float_as_uint(f);
    u += 0x7fffu + ((u >> 16) & 1u);
    return (ushort_t)(u >> 16);
}
__device__ __forceinline__ float bf2f(ushort_t h){
    return __uint_as_float(((unsigned int)h) << 16);
}
__device__ __forceinline__ unsigned int pack2(float a, float b){
    return (unsigned int)f2bf(a) | ((unsigned int)f2bf(b) << 16);
}
__device__ __forceinline__ float sigf(float v){ return 1.f / (1.f + expf(-v)); }

// ---------------- prep: pack weights to fragment-linear bf16 ----------------
__global__ __launch_bounds__(256) void prep_kernel(
    const float* __restrict__ stft_w, const float* __restrict__ w1,
    const float* __restrict__ w2, const float* __restrict__ w3,
    const float* __restrict__ w4, const float* __restrict__ wih,
    const float* __restrict__ whh, ushort_t* __restrict__ wp)
{
    int i = blockIdx.x * 256 + threadIdx.x;
    if (i >= 307200) return;
    float val = 0.f;
    if (i < PK_W1) {                                  // STFT
        int frag = i >> 9, rr = i & 511, l = rr >> 3, j = rr & 7;
        int ct = frag >> 3, kk = frag & 7;
        int kd = kk * 32 + ((l >> 4) << 3) + j;
        int n = ct * 16 + (l & 15);
        val = (n < 258) ? stft_w[n * 256 + kd] : 0.f;
    } else if (i < PK_W2) {                           // W1 (tap-major)
        int r = i - PK_W1;
        int tap = r / 20480; r -= tap * 20480;
        int frag = r >> 9, rr = r & 511, l = rr >> 3, j = rr & 7;
        int ct = frag / 5, kk = frag - ct * 5;
        int kd = kk * 32 + ((l >> 4) << 3) + j;
        int c = ct * 16 + (l & 15);
        val = (kd < 129) ? w1[c * 387 + kd * 3 + tap] : 0.f;
    } else if (i < PK_W3) {                           // W2
        int r = i - PK_W2;
        int frag = r >> 9, rr = r & 511, l = rr >> 3, j = rr & 7;
        int ct = frag / 12, kk = frag - ct * 12;
        int kd = kk * 32 + ((l >> 4) << 3) + j;
        int k = kd >> 7, f = kd & 127;
        int c = ct * 16 + (l & 15);
        val = w2[c * 384 + f * 3 + k];
    } else if (i < PK_W4) {                           // W3
        int r = i - PK_W3;
        int frag = r >> 9, rr = r & 511, l = rr >> 3, j = rr & 7;
        int ct = frag / 6, kk = frag - ct * 6;
        int kd = kk * 32 + ((l >> 4) << 3) + j;
        int k = kd >> 6, f = kd & 63;
        int c = ct * 16 + (l & 15);
        val = w3[c * 192 + f * 3 + k];
    } else if (i < PK_LSTM) {                         // W4 (center tap only)
        int r = i - PK_W4;
        int frag = r >> 9, rr = r & 511, l = rr >> 3, j = rr & 7;
        int ct = frag >> 1, kk = frag & 1;
        int kd = kk * 32 + ((l >> 4) << 3) + j;
        int c = ct * 16 + (l & 15);
        val = w4[c * 192 + kd * 3 + 1];
    } else {                                          // LSTM [feat|h] -> 512 gates
        int r = i - PK_LSTM;
        int frag = r >> 9, rr = r & 511, l = rr >> 3, j = rr & 7;
        int ct = frag >> 3, kk = frag & 7;
        int kd = kk * 32 + ((l >> 4) << 3) + j;
        int n = ct * 16 + (l & 15);
        val = (kd < 128) ? wih[n * 128 + kd] : whh[n * 128 + (kd - 128)];
    }
    wp[i] = f2bf(val);
}

// ---------------- K1: STFT (MFMA) + magnitude ----------------
// 16 batches/block, 256 thr (4 waves). M=48 rows (b*3+t), N=272 (17 ct), K=256.
__global__ __launch_bounds__(256) void stft_kernel(
    const float* __restrict__ x, const ushort_t* __restrict__ wp,
    ushort_t* __restrict__ magg)
{
    __shared__ ushort_t xs[48 * 264];   // im2col: row bt=b*3+t, k 0..255 (stride 264: 2-way free)
    __shared__ ushort_t s[48 * 264];    // STFT result bf16, cols 0..257
    const int tid = threadIdx.x, lane = tid & 63, wid = tid >> 6;
    const int l15 = lane & 15, lk = lane >> 4;

    // stage x -> im2col (each 512-sample row feeds 3 overlapping frames)
    {
        const float4* xg = (const float4*)(x + (size_t)blockIdx.x * 16 * 512);
#pragma unroll
        for (int i = 0; i < 8; ++i) {
            int idx4 = tid + i * 256;            // 0..2047
            float4 v = xg[idx4];
            int b = idx4 >> 7, c4 = idx4 & 127;
            int si = c4 * 4, t1 = si >> 7;
            unsigned int u0 = pack2(v.x, v.y), u1 = pack2(v.z, v.w);
            if (t1 < 3) {
                ushort_t* p = &xs[(b * 3 + t1) * 264 + (si & 127)];
                *(unsigned int*)p = u0; *(unsigned int*)(p + 2) = u1;
            }
            if (t1 >= 1) {
                ushort_t* p = &xs[(b * 3 + t1 - 1) * 264 + (si & 127) + 128];
                *(unsigned int*)p = u0; *(unsigned int*)(p + 2) = u1;
            }
        }
    }
    __syncthreads();

    for (int ct = wid; ct < 17; ct += 4) {
        short8 bfrag[8];
        const short8* bp = (const short8*)(wp + PK_STFT) + (size_t)(ct * 8) * 64 + lane;
#pragma unroll
        for (int kk = 0; kk < 8; ++kk) bfrag[kk] = bp[kk * 64];
        int col = ct * 16 + l15;
#pragma unroll
        for (int rt = 0; rt < 3; ++rt) {
            const ushort_t* abase = &xs[(rt * 16 + l15) * 264 + lk * 8];
            floatx4 acc = {0.f, 0.f, 0.f, 0.f};
#pragma unroll
            for (int kk = 0; kk < 8; ++kk) {
                short8 af = *(const short8*)(abase + kk * 32);
                acc = MFMA16(af, bfrag[kk], acc);
            }
            if (col < 258) {
                int r0 = rt * 16 + lk * 4;
#pragma unroll
                for (int jj = 0; jj < 4; ++jj) s[(r0 + jj) * 264 + col] = f2bf(acc[jj]);
            }
        }
    }
    __syncthreads();

    // magnitude -> global mag[B][3][160] (zero f=129..159 for conv1 K-pad)
    {
        size_t ob = (size_t)blockIdx.x * 16 * 480;
        for (int idx = tid; idx < 48 * 129; idx += 256) {
            int bt = idx / 129, f = idx - bt * 129;
            float re = bf2f(s[bt * 264 + f]);
            float im = bf2f(s[bt * 264 + 129 + f]);
            int b = bt / 3, t = bt - b * 3;
            magg[ob + b * 480 + t * 160 + f] = f2bf(sqrtf(re * re + im * im));
        }
        for (int idx = tid; idx < 48 * 31; idx += 256) {
            int bt = idx / 31, f = 129 + (idx - bt * 31);
            int b = bt / 3, t = bt - b * 3;
            magg[ob + b * 480 + t * 160 + f] = 0;
        }
    }
}

// ---------------- K2: conv1..conv4 (all MFMA) ----------------
// 32 batches/block, 256 thr (4 waves).
__global__ __launch_bounds__(256) void conv_kernel(
    const ushort_t* __restrict__ wp, const ushort_t* __restrict__ magg,
    const float* __restrict__ b1, const float* __restrict__ b2,
    const float* __restrict__ b3, const float* __restrict__ b4,
    ushort_t* __restrict__ featg)
{
    __shared__ ushort_t big[26880];      // magp [32][5][168] -> (alias) h1h [32][5][136]
    __shared__ ushort_t h2h[32 * 3 * 72];
    __shared__ ushort_t h3s[32 * 72];
    const int tid = threadIdx.x, lane = tid & 63, wid = tid >> 6;
    const int l15 = lane & 15, lk = lane >> 4;

    // stage: zero mag halo rows t'=0,4; zero h2h row t''=0; load mag t'=1..3
    {
        unsigned int* bz = (unsigned int*)big;
        for (int i = tid; i < 5376; i += 256) {          // 32b x 2rows x 84 uints
            int bb = i / 168, r = i - bb * 168;
            int tp = (r < 84) ? 0 : 4, f2 = (r < 84) ? r : r - 84;
            bz[(bb * 5 + tp) * 84 + f2] = 0u;
        }
        for (int i = tid; i < 32 * 36; i += 256) {       // h2h t''=0
            int bb = i / 36, f2 = i - bb * 36;
            ((unsigned int*)h2h)[bb * 108 + f2] = 0u;
        }
        const unsigned int* mg = (const unsigned int*)(magg + (size_t)blockIdx.x * 32 * 480);
        for (int i = tid; i < 7680; i += 256) {          // 32b x 3t x 80 uints
            int bb = i / 240, r = i - bb * 240;
            int t = r / 80, f2 = r - t * 80;
            bz[(bb * 5 + 1 + t) * 84 + f2] = mg[i];
        }
    }
    __syncthreads();

    // conv1: M=96(6rt) N=128(8ct) K=160x3taps; wave owns ct {wid, wid+4}; accs in regs
    floatx4 acc1[2][6];
#pragma unroll
    for (int ci = 0; ci < 2; ++ci)
#pragma unroll
        for (int rt = 0; rt < 6; ++rt) acc1[ci][rt] = (floatx4){0.f, 0.f, 0.f, 0.f};
#pragma unroll
    for (int ci = 0; ci < 2; ++ci) {
        int ct = wid + ci * 4;
        short8 bfrag[15];
#pragma unroll
        for (int tap = 0; tap < 3; ++tap)
#pragma unroll
            for (int kk = 0; kk < 5; ++kk)
                bfrag[tap * 5 + kk] = ((const short8*)(wp + PK_W1))[(size_t)(tap * 40 + ct * 5 + kk) * 64 + lane];
#pragma unroll
        for (int rt = 0; rt < 6; ++rt) {
            int obt = rt * 16 + l15;
            int b = obt / 3, t = obt - b * 3;
#pragma unroll
            for (int tap = 0; tap < 3; ++tap) {
                const ushort_t* abase = &big[(b * 5 + t + tap) * 168 + lk * 8];
#pragma unroll
                for (int kk = 0; kk < 5; ++kk) {
                    short8 af = *(const short8*)(abase + kk * 32);
                    acc1[ci][rt] = MFMA16(af, bfrag[tap * 5 + kk], acc1[ci][rt]);
                }
            }
        }
    }
    __syncthreads();

    // write h1h (aliased over magp): halo zeros + biased relu results
    {
        unsigned int* h1z = (unsigned int*)big;
        for (int i = tid; i < 32 * 136; i += 256) {      // rows t'=0,4: 68 uints each
            int bb = i / 136, r = i - bb * 136;
            int tp = (r < 68) ? 0 : 4, f2 = (r < 68) ? r : r - 68;
            h1z[(bb * 5 + tp) * 68 + f2] = 0u;
        }
#pragma unroll
        for (int ci = 0; ci < 2; ++ci) {
            int ct = wid + ci * 4;
            int col = ct * 16 + l15;
            float bias = b1[col];
#pragma unroll
            for (int rt = 0; rt < 6; ++rt)
#pragma unroll
                for (int jj = 0; jj < 4; ++jj) {
                    int obt = rt * 16 + lk * 4 + jj;
                    int b = obt / 3, t = obt - b * 3;
                    big[(b * 5 + t + 1) * 136 + col] = f2bf(fmaxf(acc1[ci][rt][jj] + bias, 0.f));
                }
        }
    }
    __syncthreads();

    // conv2: M=64(4rt) N=64(4ct) K=384(12kk); wave owns ct=wid
    {
        int ct = wid;
        short8 bfrag[12];
#pragma unroll
        for (int kk = 0; kk < 12; ++kk)
            bfrag[kk] = ((const short8*)(wp + PK_W2))[(size_t)(ct * 12 + kk) * 64 + lane];
        int col = ct * 16 + l15;
        float bias = b2[col];
#pragma unroll
        for (int rt = 0; rt < 4; ++rt) {
            floatx4 acc = {0.f, 0.f, 0.f, 0.f};
            int orow = rt * 16 + l15;
            int b = orow >> 1, t2 = orow & 1;
#pragma unroll
            for (int kk = 0; kk < 12; ++kk) {
                int k = kk >> 2, f = (kk & 3) * 32 + lk * 8;
                short8 af = *(const short8*)(&big[(b * 5 + 2 * t2 + k) * 136 + f]);
                acc = MFMA16(af, bfrag[kk], acc);
            }
#pragma unroll
            for (int jj = 0; jj < 4; ++jj) {
                int orw = rt * 16 + lk * 4 + jj;
                int bb = orw >> 1, tt = orw & 1;
                h2h[(bb * 3 + 1 + tt) * 72 + col] = f2bf(fmaxf(acc[jj] + bias, 0.f));
            }
        }
    }
    __syncthreads();

    // conv3: M=32(2rt) N=64(4ct) K=192(6kk); wave owns ct=wid
    {
        int ct = wid;
        short8 bfrag[6];
#pragma unroll
        for (int kk = 0; kk < 6; ++kk)
            bfrag[kk] = ((const short8*)(wp + PK_W3))[(size_t)(ct * 6 + kk) * 64 + lane];
        int col = ct * 16 + l15;
        float bias = b3[col];
#pragma unroll
        for (int rt = 0; rt < 2; ++rt) {
            floatx4 acc = {0.f, 0.f, 0.f, 0.f};
            int b = rt * 16 + l15;
#pragma unroll
            for (int kk = 0; kk < 6; ++kk) {
                int k = kk >> 1, f = (kk & 1) * 32 + lk * 8;
                short8 af = *(const short8*)(&h2h[(b * 3 + k) * 72 + f]);
                acc = MFMA16(af, bfrag[kk], acc);
            }
#pragma unroll
            for (int jj = 0; jj < 4; ++jj) {
                int bb = rt * 16 + lk * 4 + jj;
                h3s[bb * 72 + col] = f2bf(fmaxf(acc[jj] + bias, 0.f));
            }
        }
    }
    __syncthreads();

    // conv4: M=32(2rt) N=128(8ct) K=64(2kk); wave owns ct {wid, wid+4} -> feat global
    {
#pragma unroll
        for (int ci = 0; ci < 2; ++ci) {
            int ct = wid + ci * 4;
            short8 bf0 = ((const short8*)(wp + PK_W4))[(size_t)(ct * 2 + 0) * 64 + lane];
            short8 bf1 = ((const short8*)(wp + PK_W4))[(size_t)(ct * 2 + 1) * 64 + lane];
            int col = ct * 16 + l15;
            float bias = b4[col];
#pragma unroll
            for (int rt = 0; rt < 2; ++rt) {
                floatx4 acc = {0.f, 0.f, 0.f, 0.f};
                int b = rt * 16 + l15;
                short8 a0 = *(const short8*)(&h3s[b * 72 + lk * 8]);
                short8 a1 = *(const short8*)(&h3s[b * 72 + 32 + lk * 8]);
                acc = MFMA16(a0, bf0, acc);
                acc = MFMA16(a1, bf1, acc);
#pragma unroll
                for (int jj = 0; jj < 4; ++jj) {
                    int bb = rt * 16 + lk * 4 + jj;
                    featg[((size_t)blockIdx.x * 32 + bb) * 128 + col] = f2bf(fmaxf(acc[jj] + bias, 0.f));
                }
            }
        }
    }
}

// ---------------- K3: LSTM gates (MFMA) + cell + head ----------------
// 32 batches/block, 256 thr (4 waves). M=32(2rt) N=512(32ct) K=256(8kk).
// Wave owns cts {wid, wid+4, ..., wid+28}: i/f/g/o columns for a given cc land
// in the SAME lane -> gates stay in registers, no LDS round-trip.
__global__ __launch_bounds__(256) void lstm_kernel(
    const ushort_t* __restrict__ featg, const float* __restrict__ state,
    const ushort_t* __restrict__ wp, const float* __restrict__ bih,
    const float* __restrict__ bhh, const float* __restrict__ fw,
    const float* __restrict__ fbp, float* __restrict__ out, int B)
{
    __shared__ ushort_t inc[32 * 264];   // cols 0..127 feat, 128..255 h_prev
    __shared__ float red[128];
    const int tid = threadIdx.x, lane = tid & 63, wid = tid >> 6;
    const int l15 = lane & 15, lk = lane >> 4;
    const size_t b0 = (size_t)blockIdx.x * 32;

    {
        const unsigned int* fg = (const unsigned int*)(featg + b0 * 128);
        unsigned int* ip = (unsigned int*)inc;
        for (int i = tid; i < 2048; i += 256) {
            int bb = i >> 6, f2 = i & 63;
            ip[bb * 132 + f2] = fg[i];
        }
        const float* hp = state + b0 * 128;
        for (int i = tid; i < 2048; i += 256) {
            int bb = i >> 6, c2 = i & 63;
            float2 v = *(const float2*)&hp[bb * 128 + c2 * 2];
            ip[bb * 132 + 64 + c2] = pack2(v.x, v.y);
        }
    }
    __syncthreads();

    floatx4 acc[8][2];
#pragma unroll
    for (int ci = 0; ci < 8; ++ci) {
        int ct = wid + ci * 4;
        short8 bfrag[8];
#pragma unroll
        for (int kk = 0; kk < 8; ++kk)
            bfrag[kk] = ((const short8*)(wp + PK_LSTM))[(size_t)(ct * 8 + kk) * 64 + lane];
#pragma unroll
        for (int rt = 0; rt < 2; ++rt) {
            const ushort_t* abase = &inc[(rt * 16 + l15) * 264 + lk * 8];
            floatx4 a = {0.f, 0.f, 0.f, 0.f};
#pragma unroll
            for (int kk = 0; kk < 8; ++kk) {
                short8 af = *(const short8*)(abase + kk * 32);
                a = MFMA16(af, bfrag[kk], a);
            }
            acc[ci][rt] = a;
        }
    }

    // cell update + head partials (gates all in regs)
    const float* cprev = state + (size_t)B * 128;
    float* outh = out + B;
    float* outc = out + B + (size_t)B * 128;
    float ph[2][4];
#pragma unroll
    for (int rt = 0; rt < 2; ++rt)
#pragma unroll
        for (int jj = 0; jj < 4; ++jj) ph[rt][jj] = 0.f;

#pragma unroll
    for (int g2 = 0; g2 < 2; ++g2) {
        int cc = (wid + g2 * 4) * 16 + l15;
        float bi = bih[cc] + bhh[cc];
        float bf_ = bih[cc + 128] + bhh[cc + 128];
        float bg = bih[cc + 256] + bhh[cc + 256];
        float bo = bih[cc + 384] + bhh[cc + 384];
        float fwv = fw[cc];
#pragma unroll
        for (int rt = 0; rt < 2; ++rt)
#pragma unroll
            for (int jj = 0; jj < 4; ++jj) {
                int row = rt * 16 + lk * 4 + jj;
                size_t gb = b0 + row;
                float gi = acc[g2][rt][jj] + bi;
                float gf = acc[g2 + 2][rt][jj] + bf_;
                float gg = acc[g2 + 4][rt][jj] + bg;
                float go = acc[g2 + 6][rt][jj] + bo;
                float cp = cprev[gb * 128 + cc];
                float cn = sigf(gf) * cp + sigf(gi) * tanhf(gg);
                float hn = sigf(go) * tanhf(cn);
                outh[gb * 128 + cc] = hn;
                outc[gb * 128 + cc] = cn;
                ph[rt][jj] += fmaxf(hn, 0.f) * fwv;
            }
    }

    // head: reduce over the 16 lanes of each (l>>4) group, then across waves
#pragma unroll
    for (int rt = 0; rt < 2; ++rt)
#pragma unroll
        for (int jj = 0; jj < 4; ++jj) {
            float v = ph[rt][jj];
            v += __shfl_xor(v, 1, 64);
            v += __shfl_xor(v, 2, 64);
            v += __shfl_xor(v, 4, 64);
            v += __shfl_xor(v, 8, 64);
            if (l15 == 0) red[wid * 32 + rt * 16 + lk * 4 + jj] = v;
        }
    __syncthreads();
    if (tid < 32) {
        float v = red[tid] + red[32 + tid] + red[64 + tid] + red[96 + tid];
        out[b0 + tid] = sigf(v + fbp[0]);
    }
}

extern "C" void kernel_launch(void* const* d_in, const int* in_sizes, int n_in,
                              void* d_out, int out_size, void* d_ws, size_t ws_size,
                              hipStream_t stream) {
    const float* x      = (const float*)d_in[0];
    const float* state  = (const float*)d_in[1];
    const float* stft_w = (const float*)d_in[2];
    const float* w1     = (const float*)d_in[3];
    const float* b1     = (const float*)d_in[4];
    const float* w2     = (const float*)d_in[5];
    const float* b2     = (const float*)d_in[6];
    const float* w3     = (const float*)d_in[7];
    const float* b3     = (const float*)d_in[8];
    const float* w4     = (const float*)d_in[9];
    const float* b4     = (const float*)d_in[10];
    const float* wih    = (const float*)d_in[11];
    const float* whh    = (const float*)d_in[12];
    const float* bih    = (const float*)d_in[13];
    const float* bhh    = (const float*)d_in[14];
    const float* fw     = (const float*)d_in[15];
    const float* fbp    = (const float*)d_in[16];

    ushort_t* wp = (ushort_t*)d_ws;
    const int B = in_sizes[0] / 512;   // 16384

    prep_kernel<<<1200, 256, 0, stream>>>(stft_w, w1, w2, w3, w4, wih, whh, wp);
    stft_kernel<<<B / 16, 256, 0, stream>>>(x, wp, wp + OFF_MAG);
    conv_kernel<<<B / 32, 256, 0, stream>>>(wp, wp + OFF_MAG, b1, b2, b3, b4, wp + OFF_FEAT);
    lstm_kernel<<<B / 32, 256, 0, stream>>>(wp + OFF_FEAT, state, wp, bih, bhh, fw, fbp,
                                            (float*)d_out, B);
}

// Round 3
// 73.692 us; speedup vs baseline: 5.8853x; 1.1368x over previous
//
#include <hip/hip_runtime.h>
#include <math.h>

typedef unsigned short ushort_t;
typedef short short8 __attribute__((ext_vector_type(8)));
typedef float floatx4 __attribute__((ext_vector_type(4)));

#define MFMA16(a,b,c) __builtin_amdgcn_mfma_f32_16x16x32_bf16((a),(b),(c),0,0,0)

// ---------------- ws layout (ushort/bf16 elements) ----------------
#define PK_STFT 0          // 17ct x 8kk          = 69632   B[k=0..255][n=0..271], n>=258 -> 0
#define PK_W1   69632      // 3tap x (8ct x 5kk)  = 61440   B[f=0..159][c], f>=129 -> 0
#define PK_W2   131072     // 4ct x 12kk          = 24576   B[k*128+f][c]
#define PK_W3   155648     // 4ct x 6kk           = 12288   B[k*64+f][c]
#define PK_W4   167936     // 8ct x 2kk           = 8192    B[f=0..63][c]  (tap k=1 only)
#define PK_LSTM 176128     // 32ct x 8kk          = 131072  B[k=0..255][n], k<128: w_ih, else w_hh
#define OFF_MAG 307200     // [B][3][160] bf16
#define OFF_FEAT 8171520   // [B][128] bf16

__device__ __forceinline__ ushort_t f2bf(float f){
    unsigned int u = __float_as_uint(f);
    u += 0x7fffu + ((u >> 16) & 1u);
    return (ushort_t)(u >> 16);
}
__device__ __forceinline__ float bf2f(ushort_t h){
    return __uint_as_float(((unsigned int)h) << 16);
}
__device__ __forceinline__ unsigned int pack2(float a, float b){
    return (unsigned int)f2bf(a) | ((unsigned int)f2bf(b) << 16);
}
// fast sigmoid/tanh via v_exp_f32 (2^x) + v_rcp_f32
__device__ __forceinline__ float fsig(float v){
    return __builtin_amdgcn_rcpf(1.f + __builtin_amdgcn_exp2f(-1.44269504f * v));
}
__device__ __forceinline__ float ftanh(float v){
    return 2.f * __builtin_amdgcn_rcpf(1.f + __builtin_amdgcn_exp2f(-2.88539008f * v)) - 1.f;
}

// ---------------- prep: pack weights to fragment-linear bf16 ----------------
__global__ __launch_bounds__(256) void prep_kernel(
    const float* __restrict__ stft_w, const float* __restrict__ w1,
    const float* __restrict__ w2, const float* __restrict__ w3,
    const float* __restrict__ w4, const float* __restrict__ wih,
    const float* __restrict__ whh, ushort_t* __restrict__ wp)
{
    int i = blockIdx.x * 256 + threadIdx.x;
    if (i >= 307200) return;
    float val = 0.f;
    if (i < PK_W1) {                                  // STFT
        int frag = i >> 9, rr = i & 511, l = rr >> 3, j = rr & 7;
        int ct = frag >> 3, kk = frag & 7;
        int kd = kk * 32 + ((l >> 4) << 3) + j;
        int n = ct * 16 + (l & 15);
        val = (n < 258) ? stft_w[n * 256 + kd] : 0.f;
    } else if (i < PK_W2) {                           // W1 (tap-major)
        int r = i - PK_W1;
        int tap = r / 20480; r -= tap * 20480;
        int frag = r >> 9, rr = r & 511, l = rr >> 3, j = rr & 7;
        int ct = frag / 5, kk = frag - ct * 5;
        int kd = kk * 32 + ((l >> 4) << 3) + j;
        int c = ct * 16 + (l & 15);
        val = (kd < 129) ? w1[c * 387 + kd * 3 + tap] : 0.f;
    } else if (i < PK_W3) {                           // W2
        int r = i - PK_W2;
        int frag = r >> 9, rr = r & 511, l = rr >> 3, j = rr & 7;
        int ct = frag / 12, kk = frag - ct * 12;
        int kd = kk * 32 + ((l >> 4) << 3) + j;
        int k = kd >> 7, f = kd & 127;
        int c = ct * 16 + (l & 15);
        val = w2[c * 384 + f * 3 + k];
    } else if (i < PK_W4) {                           // W3
        int r = i - PK_W3;
        int frag = r >> 9, rr = r & 511, l = rr >> 3, j = rr & 7;
        int ct = frag / 6, kk = frag - ct * 6;
        int kd = kk * 32 + ((l >> 4) << 3) + j;
        int k = kd >> 6, f = kd & 63;
        int c = ct * 16 + (l & 15);
        val = w3[c * 192 + f * 3 + k];
    } else if (i < PK_LSTM) {                         // W4 (center tap only)
        int r = i - PK_W4;
        int frag = r >> 9, rr = r & 511, l = rr >> 3, j = rr & 7;
        int ct = frag >> 1, kk = frag & 1;
        int kd = kk * 32 + ((l >> 4) << 3) + j;
        int c = ct * 16 + (l & 15);
        val = w4[c * 192 + kd * 3 + 1];
    } else {                                          // LSTM [feat|h] -> 512 gates
        int r = i - PK_LSTM;
        int frag = r >> 9, rr = r & 511, l = rr >> 3, j = rr & 7;
        int ct = frag >> 3, kk = frag & 7;
        int kd = kk * 32 + ((l >> 4) << 3) + j;
        int n = ct * 16 + (l & 15);
        val = (kd < 128) ? wih[n * 128 + kd] : whh[n * 128 + (kd - 128)];
    }
    wp[i] = f2bf(val);
}

// ---------------- K1: STFT (MFMA) + magnitude ----------------
// 16 batches/block, 256 thr (4 waves). M=48 rows (b*3+t), N=272 (17 ct), K=256.
__global__ __launch_bounds__(256) void stft_kernel(
    const float* __restrict__ x, const ushort_t* __restrict__ wp,
    ushort_t* __restrict__ magg)
{
    __shared__ ushort_t xs[48 * 264];
    __shared__ ushort_t s[48 * 264];
    const int tid = threadIdx.x, lane = tid & 63, wid = tid >> 6;
    const int l15 = lane & 15, lk = lane >> 4;

    {
        const float4* xg = (const float4*)(x + (size_t)blockIdx.x * 16 * 512);
#pragma unroll
        for (int i = 0; i < 8; ++i) {
            int idx4 = tid + i * 256;
            float4 v = xg[idx4];
            int b = idx4 >> 7, c4 = idx4 & 127;
            int si = c4 * 4, t1 = si >> 7;
            unsigned int u0 = pack2(v.x, v.y), u1 = pack2(v.z, v.w);
            if (t1 < 3) {
                ushort_t* p = &xs[(b * 3 + t1) * 264 + (si & 127)];
                *(unsigned int*)p = u0; *(unsigned int*)(p + 2) = u1;
            }
            if (t1 >= 1) {
                ushort_t* p = &xs[(b * 3 + t1 - 1) * 264 + (si & 127) + 128];
                *(unsigned int*)p = u0; *(unsigned int*)(p + 2) = u1;
            }
        }
    }
    __syncthreads();

    for (int ct = wid; ct < 17; ct += 4) {
        short8 bfrag[8];
        const short8* bp = (const short8*)(wp + PK_STFT) + (size_t)(ct * 8) * 64 + lane;
#pragma unroll
        for (int kk = 0; kk < 8; ++kk) bfrag[kk] = bp[kk * 64];
        int col = ct * 16 + l15;
#pragma unroll
        for (int rt = 0; rt < 3; ++rt) {
            const ushort_t* abase = &xs[(rt * 16 + l15) * 264 + lk * 8];
            floatx4 acc = {0.f, 0.f, 0.f, 0.f};
#pragma unroll
            for (int kk = 0; kk < 8; ++kk) {
                short8 af = *(const short8*)(abase + kk * 32);
                acc = MFMA16(af, bfrag[kk], acc);
            }
            if (col < 258) {
                int r0 = rt * 16 + lk * 4;
#pragma unroll
                for (int jj = 0; jj < 4; ++jj) s[(r0 + jj) * 264 + col] = f2bf(acc[jj]);
            }
        }
    }
    __syncthreads();

    {
        size_t ob = (size_t)blockIdx.x * 16 * 480;
        for (int idx = tid; idx < 48 * 129; idx += 256) {
            int bt = idx / 129, f = idx - bt * 129;
            float re = bf2f(s[bt * 264 + f]);
            float im = bf2f(s[bt * 264 + 129 + f]);
            int b = bt / 3, t = bt - b * 3;
            magg[ob + b * 480 + t * 160 + f] = f2bf(sqrtf(re * re + im * im));
        }
        for (int idx = tid; idx < 48 * 31; idx += 256) {
            int bt = idx / 31, f = 129 + (idx - bt * 31);
            int b = bt / 3, t = bt - b * 3;
            magg[ob + b * 480 + t * 160 + f] = 0;
        }
    }
}

// ---------------- K2: conv1..conv4 (all MFMA), 16 batches/block ----------------
__global__ __launch_bounds__(256) void conv_kernel(
    const ushort_t* __restrict__ wp, const ushort_t* __restrict__ magg,
    const float* __restrict__ b1, const float* __restrict__ b2,
    const float* __restrict__ b3, const float* __restrict__ b4,
    ushort_t* __restrict__ featg)
{
    __shared__ ushort_t big[13440];      // magp [16][5][168] -> (alias) h1h [16][5][136]
    __shared__ ushort_t h2h[16 * 3 * 72];
    __shared__ ushort_t h3s[16 * 72];
    const int tid = threadIdx.x, lane = tid & 63, wid = tid >> 6;
    const int l15 = lane & 15, lk = lane >> 4;

    // stage: halo rows t'=0,4 zero; h2h row 0 zero; mag rows t'=1..3
    {
        unsigned int* bz = (unsigned int*)big;
        for (int i = tid; i < 2688; i += 256) {
            int bb = i / 168, r = i - bb * 168;
            int tp = (r < 84) ? 0 : 4, f2 = (r < 84) ? r : r - 84;
            bz[(bb * 5 + tp) * 84 + f2] = 0u;
        }
        for (int i = tid; i < 576; i += 256) {
            int bb = i / 36, f2 = i - bb * 36;
            ((unsigned int*)h2h)[bb * 108 + f2] = 0u;
        }
        const unsigned int* mg = (const unsigned int*)(magg + (size_t)blockIdx.x * 16 * 480);
        for (int i = tid; i < 3840; i += 256) {
            int bb = i / 240, r = i - bb * 240;
            int t = r / 80, f2 = r - t * 80;
            bz[(bb * 5 + 1 + t) * 84 + f2] = mg[i];
        }
    }
    __syncthreads();

    // conv1: M=48(3rt) N=128(8ct) K=160x3taps; wave owns ct {wid, wid+4}
    floatx4 acc1[2][3];
#pragma unroll
    for (int ci = 0; ci < 2; ++ci)
#pragma unroll
        for (int rt = 0; rt < 3; ++rt) acc1[ci][rt] = (floatx4){0.f, 0.f, 0.f, 0.f};
#pragma unroll
    for (int ci = 0; ci < 2; ++ci) {
        int ct = wid + ci * 4;
        short8 bfrag[15];
#pragma unroll
        for (int tap = 0; tap < 3; ++tap)
#pragma unroll
            for (int kk = 0; kk < 5; ++kk)
                bfrag[tap * 5 + kk] = ((const short8*)(wp + PK_W1))[(size_t)(tap * 40 + ct * 5 + kk) * 64 + lane];
#pragma unroll
        for (int rt = 0; rt < 3; ++rt) {
            int obt = rt * 16 + l15;
            int b = obt / 3, t = obt - b * 3;
#pragma unroll
            for (int tap = 0; tap < 3; ++tap) {
                const ushort_t* abase = &big[(b * 5 + t + tap) * 168 + lk * 8];
#pragma unroll
                for (int kk = 0; kk < 5; ++kk) {
                    short8 af = *(const short8*)(abase + kk * 32);
                    acc1[ci][rt] = MFMA16(af, bfrag[tap * 5 + kk], acc1[ci][rt]);
                }
            }
        }
    }
    __syncthreads();

    // write h1h (aliased over magp): halo zeros + biased relu results
    {
        unsigned int* h1z = (unsigned int*)big;
        for (int i = tid; i < 2176; i += 256) {
            int bb = i / 136, r = i - bb * 136;
            int tp = (r < 68) ? 0 : 4, f2 = (r < 68) ? r : r - 68;
            h1z[(bb * 5 + tp) * 68 + f2] = 0u;
        }
#pragma unroll
        for (int ci = 0; ci < 2; ++ci) {
            int ct = wid + ci * 4;
            int col = ct * 16 + l15;
            float bias = b1[col];
#pragma unroll
            for (int rt = 0; rt < 3; ++rt)
#pragma unroll
                for (int jj = 0; jj < 4; ++jj) {
                    int obt = rt * 16 + lk * 4 + jj;
                    int b = obt / 3, t = obt - b * 3;
                    big[(b * 5 + t + 1) * 136 + col] = f2bf(fmaxf(acc1[ci][rt][jj] + bias, 0.f));
                }
        }
    }
    __syncthreads();

    // conv2: M=32(2rt) N=64(4ct) K=384(12kk); wave owns ct=wid
    {
        int ct = wid;
        short8 bfrag[12];
#pragma unroll
        for (int kk = 0; kk < 12; ++kk)
            bfrag[kk] = ((const short8*)(wp + PK_W2))[(size_t)(ct * 12 + kk) * 64 + lane];
        int col = ct * 16 + l15;
        float bias = b2[col];
#pragma unroll
        for (int rt = 0; rt < 2; ++rt) {
            floatx4 acc = {0.f, 0.f, 0.f, 0.f};
            int orow = rt * 16 + l15;
            int b = orow >> 1, t2 = orow & 1;
#pragma unroll
            for (int kk = 0; kk < 12; ++kk) {
                int k = kk >> 2, f = (kk & 3) * 32 + lk * 8;
                short8 af = *(const short8*)(&big[(b * 5 + 2 * t2 + k) * 136 + f]);
                acc = MFMA16(af, bfrag[kk], acc);
            }
#pragma unroll
            for (int jj = 0; jj < 4; ++jj) {
                int orw = rt * 16 + lk * 4 + jj;
                int bb = orw >> 1, tt = orw & 1;
                h2h[(bb * 3 + 1 + tt) * 72 + col] = f2bf(fmaxf(acc[jj] + bias, 0.f));
            }
        }
    }
    __syncthreads();

    // conv3: M=16(1rt) N=64(4ct) K=192(6kk); wave owns ct=wid
    {
        int ct = wid;
        short8 bfrag[6];
#pragma unroll
        for (int kk = 0; kk < 6; ++kk)
            bfrag[kk] = ((const short8*)(wp + PK_W3))[(size_t)(ct * 6 + kk) * 64 + lane];
        int col = ct * 16 + l15;
        float bias = b3[col];
        floatx4 acc = {0.f, 0.f, 0.f, 0.f};
        int b = l15;
#pragma unroll
        for (int kk = 0; kk < 6; ++kk) {
            int k = kk >> 1, f = (kk & 1) * 32 + lk * 8;
            short8 af = *(const short8*)(&h2h[(b * 3 + k) * 72 + f]);
            acc = MFMA16(af, bfrag[kk], acc);
        }
#pragma unroll
        for (int jj = 0; jj < 4; ++jj) {
            int bb = lk * 4 + jj;
            h3s[bb * 72 + col] = f2bf(fmaxf(acc[jj] + bias, 0.f));
        }
    }
    __syncthreads();

    // conv4: M=16(1rt) N=128(8ct) K=64(2kk); wave owns ct {wid, wid+4} -> feat global
    {
#pragma unroll
        for (int ci = 0; ci < 2; ++ci) {
            int ct = wid + ci * 4;
            short8 bf0 = ((const short8*)(wp + PK_W4))[(size_t)(ct * 2 + 0) * 64 + lane];
            short8 bf1 = ((const short8*)(wp + PK_W4))[(size_t)(ct * 2 + 1) * 64 + lane];
            int col = ct * 16 + l15;
            float bias = b4[col];
            floatx4 acc = {0.f, 0.f, 0.f, 0.f};
            int b = l15;
            short8 a0 = *(const short8*)(&h3s[b * 72 + lk * 8]);
            short8 a1 = *(const short8*)(&h3s[b * 72 + 32 + lk * 8]);
            acc = MFMA16(a0, bf0, acc);
            acc = MFMA16(a1, bf1, acc);
#pragma unroll
            for (int jj = 0; jj < 4; ++jj) {
                int bb = lk * 4 + jj;
                featg[((size_t)blockIdx.x * 16 + bb) * 128 + col] = f2bf(fmaxf(acc[jj] + bias, 0.f));
            }
        }
    }
}

// ---------------- K3: LSTM gates (MFMA) + cell + head ----------------
// 32 batches/block, 512 thr (8 waves). M=32(2rt) N=512(32ct) K=256(8kk).
// Wave w owns cts {w, w+8, w+16, w+24}: the i/f/g/o columns for cc=w*16+l15
// land in the same lane -> gates stay in registers.
__global__ __launch_bounds__(512) void lstm_kernel(
    const ushort_t* __restrict__ featg, const float* __restrict__ state,
    const ushort_t* __restrict__ wp, const float* __restrict__ bih,
    const float* __restrict__ bhh, const float* __restrict__ fw,
    const float* __restrict__ fbp, float* __restrict__ out, int B)
{
    __shared__ ushort_t inc[32 * 264];   // cols 0..127 feat, 128..255 h_prev
    __shared__ float red[256];
    const int tid = threadIdx.x, lane = tid & 63, wid = tid >> 6;
    const int l15 = lane & 15, lk = lane >> 4;
    const size_t b0 = (size_t)blockIdx.x * 32;
    const int cc = wid * 16 + l15;

    // prefetch c_prev (consumed after MFMA; latency hides under it)
    const float* cprev = state + (size_t)B * 128;
    float cpv[2][4];
#pragma unroll
    for (int rt = 0; rt < 2; ++rt)
#pragma unroll
        for (int jj = 0; jj < 4; ++jj)
            cpv[rt][jj] = cprev[(b0 + rt * 16 + lk * 4 + jj) * 128 + cc];

    {
        const unsigned int* fg = (const unsigned int*)(featg + b0 * 128);
        unsigned int* ip = (unsigned int*)inc;
        for (int i = tid; i < 2048; i += 512) {
            int bb = i >> 6, f2 = i & 63;
            ip[bb * 132 + f2] = fg[i];
        }
        const float* hp = state + b0 * 128;
        for (int i = tid; i < 2048; i += 512) {
            int bb = i >> 6, c2 = i & 63;
            float2 v = *(const float2*)&hp[bb * 128 + c2 * 2];
            ip[bb * 132 + 64 + c2] = pack2(v.x, v.y);
        }
    }
    __syncthreads();

    floatx4 acc[4][2];
#pragma unroll
    for (int ci = 0; ci < 4; ++ci) {
        int ct = wid + ci * 8;
        short8 bfrag[8];
#pragma unroll
        for (int kk = 0; kk < 8; ++kk)
            bfrag[kk] = ((const short8*)(wp + PK_LSTM))[(size_t)(ct * 8 + kk) * 64 + lane];
#pragma unroll
        for (int rt = 0; rt < 2; ++rt) {
            const ushort_t* abase = &inc[(rt * 16 + l15) * 264 + lk * 8];
            floatx4 a = {0.f, 0.f, 0.f, 0.f};
#pragma unroll
            for (int kk = 0; kk < 8; ++kk) {
                short8 af = *(const short8*)(abase + kk * 32);
                a = MFMA16(af, bfrag[kk], a);
            }
            acc[ci][rt] = a;
        }
    }

    // cell update + head partials (gates all in regs)
    float* outh = out + B;
    float* outc = out + B + (size_t)B * 128;
    float ph[2][4];
    const float bi = bih[cc] + bhh[cc];
    const float bf_ = bih[cc + 128] + bhh[cc + 128];
    const float bg = bih[cc + 256] + bhh[cc + 256];
    const float bo = bih[cc + 384] + bhh[cc + 384];
    const float fwv = fw[cc];
#pragma unroll
    for (int rt = 0; rt < 2; ++rt)
#pragma unroll
        for (int jj = 0; jj < 4; ++jj) {
            int row = rt * 16 + lk * 4 + jj;
            size_t gb = b0 + row;
            float gi = acc[0][rt][jj] + bi;
            float gf = acc[1][rt][jj] + bf_;
            float gg = acc[2][rt][jj] + bg;
            float go = acc[3][rt][jj] + bo;
            float cn = fsig(gf) * cpv[rt][jj] + fsig(gi) * ftanh(gg);
            float hn = fsig(go) * ftanh(cn);
            outh[gb * 128 + cc] = hn;
            outc[gb * 128 + cc] = cn;
            ph[rt][jj] = fmaxf(hn, 0.f) * fwv;
        }

    // head: reduce the 16 cc-lanes of each l-group, stash per (wave,row)
#pragma unroll
    for (int rt = 0; rt < 2; ++rt)
#pragma unroll
        for (int jj = 0; jj < 4; ++jj) {
            float v = ph[rt][jj];
            v += __shfl_xor(v, 1, 64);
            v += __shfl_xor(v, 2, 64);
            v += __shfl_xor(v, 4, 64);
            v += __shfl_xor(v, 8, 64);
            if (l15 == 0) red[wid * 32 + rt * 16 + lk * 4 + jj] = v;
        }
    __syncthreads();
    if (tid < 32) {
        float v = 0.f;
#pragma unroll
        for (int w = 0; w < 8; ++w) v += red[w * 32 + tid];
        out[b0 + tid] = fsig(v + fbp[0]);
    }
}

extern "C" void kernel_launch(void* const* d_in, const int* in_sizes, int n_in,
                              void* d_out, int out_size, void* d_ws, size_t ws_size,
                              hipStream_t stream) {
    const float* x      = (const float*)d_in[0];
    const float* state  = (const float*)d_in[1];
    const float* stft_w = (const float*)d_in[2];
    const float* w1     = (const float*)d_in[3];
    const float* b1     = (const float*)d_in[4];
    const float* w2     = (const float*)d_in[5];
    const float* b2     = (const float*)d_in[6];
    const float* w3     = (const float*)d_in[7];
    const float* b3     = (const float*)d_in[8];
    const float* w4     = (const float*)d_in[9];
    const float* b4     = (const float*)d_in[10];
    const float* wih    = (const float*)d_in[11];
    const float* whh    = (const float*)d_in[12];
    const float* bih    = (const float*)d_in[13];
    const float* bhh    = (const float*)d_in[14];
    const float* fw     = (const float*)d_in[15];
    const float* fbp    = (const float*)d_in[16];

    ushort_t* wp = (ushort_t*)d_ws;
    const int B = in_sizes[0] / 512;   // 16384

    prep_kernel<<<1200, 256, 0, stream>>>(stft_w, w1, w2, w3, w4, wih, whh, wp);
    stft_kernel<<<B / 16, 256, 0, stream>>>(x, wp, wp + OFF_MAG);
    conv_kernel<<<B / 16, 256, 0, stream>>>(wp, wp + OFF_MAG, b1, b2, b3, b4, wp + OFF_FEAT);
    lstm_kernel<<<B / 32, 512, 0, stream>>>(wp + OFF_FEAT, state, wp, bih, bhh, fw, fbp,
                                            (float*)d_out, B);
}